// Round 11
// baseline (147.509 us; speedup 1.0000x reference)
//
#include <hip/hip_runtime.h>
#include <math.h>

#define L_SEQ 256
#define TILE 32
#define NSEG 8

typedef __attribute__((ext_vector_type(2))) float f32x2;
typedef __attribute__((ext_vector_type(4))) float f32x4;
typedef __attribute__((ext_vector_type(8))) _Float16 f16x8;

__device__ __forceinline__ f32x2 fma2(f32x2 a, f32x2 b, f32x2 c) {
    return __builtin_elementwise_fma(a, b, c);
}
__device__ __forceinline__ f32x2 splat2(float x) { f32x2 v = {x, x}; return v; }
__device__ __forceinline__ float silu_f(float x) { return x / (1.f + __expf(-x)); }
__device__ __forceinline__ float sp2_f(float x) {
    return log2f(1.f + exp2f(x * 1.44269504f)) * 0.69314718f;
}

// ---- prep (one launch, 6 blocks):
//  blocks 0..4: WT[160][128] f16 = [x_proj[:,:4]@dt_w | x_proj[:,4:36]]^T
//  block 5:     W2[256][32] f16 (conv+expansion+in_proj folded) + bias2
__global__ __launch_bounds__(256)
void k_prep(const float* __restrict__ exp_w, const float* __restrict__ exp_b,
            const float* __restrict__ in_proj_w, const float* __restrict__ x_proj_w,
            const float* __restrict__ dt_w,
            const float* __restrict__ conv_w, const float* __restrict__ conv_b,
            _Float16* __restrict__ WT, _Float16* __restrict__ W2, float* __restrict__ bias2)
{
    const int t = threadIdx.x, blk = blockIdx.x;
    if (blk < 5) {
        const int base = blk * 4096;
        for (int i = base + t; i < base + 4096; i += 256) {
            const int row = i >> 7, k = i & 127;
            float v;
            if (row < 128) {
                v = x_proj_w[k * 36 + 0] * dt_w[row]
                  + x_proj_w[k * 36 + 1] * dt_w[128 + row]
                  + x_proj_w[k * 36 + 2] * dt_w[256 + row]
                  + x_proj_w[k * 36 + 3] * dt_w[384 + row];
            } else {
                v = x_proj_w[k * 36 + 4 + (row - 128)];
            }
            WT[i] = (_Float16)v;
        }
    } else {
        // thread t<128 -> xc channel d=t ; t>=128 -> z channel d=t-128
        const int d = t & 127;
        const int col = (t < 128) ? d : (128 + d);
        float w0 = 0, w1 = 0, w2 = 0, w3 = 0, bb = 0;
        for (int k = 0; k < 64; ++k) {
            float w = in_proj_w[k * 256 + col];
            w0 = fmaf(exp_w[k], w, w0);
            w1 = fmaf(exp_w[64 + k], w, w1);
            w2 = fmaf(exp_w[128 + k], w, w2);
            w3 = fmaf(exp_w[192 + k], w, w3);
            bb = fmaf(exp_b[k], w, bb);
        }
        const float wx[4] = {w0, w1, w2, w3};
        if (t < 128) {
            for (int j = 0; j < 32; ++j) {
                float v = 0.f;
                if (j < 16)      v = conv_w[d * 4 + (j >> 2)] * wx[j & 3];
                else if (j < 20) v = conv_w[d * 4 + (j - 16)] * bb;
                W2[d * 32 + j] = (_Float16)v;
            }
            bias2[d] = conv_b[d];
        } else {
            for (int j = 0; j < 32; ++j) {
                float v = 0.f;
                if (j >= 12 && j < 16) v = wx[j - 12];
                else if (j == 19)      v = bb;
                W2[(128 + d) * 32 + j] = (_Float16)v;
            }
        }
    }
}

// ---- fused Mamba: grid = B*4 blocks x 512 threads; each block = 2 segments ----
// Phases F/A/C build both 32-step tiles with all 8 waves; phase E scans both
// segments concurrently (waves 0-3 -> seg 2j, waves 4-7 -> seg 2j+1).
__global__ __launch_bounds__(512, 2)
void mamba_seg2(const float* __restrict__ reads,
                const _Float16* __restrict__ WT, const _Float16* __restrict__ W2,
                const float* __restrict__ bias2, const float* __restrict__ dt_b,
                const float* __restrict__ A_log, const float* __restrict__ D_skip,
                f16x8* __restrict__ QPK, float* __restrict__ GS,
                float* __restrict__ CZ, float* __restrict__ SL, int Bn)
{
    const int bx = blockIdx.x;
    const int b = bx >> 2, jp = bx & 3;
    const int t = threadIdx.x;
    const int lane256 = t & 255, wg = t >> 8;     // phase-E: segment half
    const int dd = lane256 >> 1, g = lane256 & 1; // channel, state-half
    const int sidx = jp * 2 + wg;

    __shared__ __align__(16) _Float16 F2[2][32 * 40];
    __shared__ __align__(16) _Float16 XC2[2][32 * 136];
    __shared__ __align__(16) float    BC2[2][32 * 32];
    __shared__ _Float16               ZS2[2][32 * 128];
    __shared__ _Float16               DE2[2][32 * 128];

    // phase-E per-lane params
    const float dskip = D_skip[dd];
    const float c1 = -1.44269504f * (float)(8 * g + 1);
    bool structured = true;
#pragma unroll
    for (int k = 0; k < 8; ++k) {
        float a = -__expf(A_log[dd * 16 + g * 8 + k]);
        structured = structured && (fabsf(a + (float)(g * 8 + k + 1)) < 1e-3f);
    }

    // ---- build F for both tiles: taps(16) | bias indicators(4) | pad ----
    for (int i = t; i < 2 * 32 * 40; i += 512) {
        const int tau = i / 1280, r = i - tau * 1280;
        const int l = r / 40, j = r - l * 40;
        const int l_off = jp * 64 + tau * 32;
        _Float16 v = (_Float16)0.f;
        if (j < 16) {
            const int row = l_off + l - 3 + (j >> 2);
            if (row >= 0) v = (_Float16)reads[((size_t)b * L_SEQ + row) * 4 + (j & 3)];
        } else if (j < 20) {
            v = (l_off + l - 3 + (j - 16) >= 0) ? (_Float16)1.f : (_Float16)0.f;
        }
        F2[0][i] = v;   // F2 is contiguous [2][1280]
    }
    __syncthreads();

    const int lane = t & 63, wv = t >> 6;
    const int fcol = lane & 15, kq = lane >> 4, rbase = kq * 4;

    // ---- phase A: 64 MFMA tile-tasks (both tiles) -> XC, ZS ----
#pragma unroll
    for (int i = 0; i < 8; ++i) {
        const int tt = wv + 8 * i;
        const int tau = tt >> 5, tid = tt & 31;
        const int m = tid & 1, n = tid >> 1;
        f16x8 af = *(const f16x8*)&F2[tau][(m * 16 + fcol) * 40 + kq * 8];
        f16x8 bf = *(const f16x8*)&W2[(n * 16 + fcol) * 32 + kq * 8];
        f32x4 acc = {0.f, 0.f, 0.f, 0.f};
        acc = __builtin_amdgcn_mfma_f32_16x16x32_f16(af, bf, acc, 0, 0, 0);
        if (n < 8) {
            const int ch = n * 16 + fcol;
            const float bv = bias2[ch];
#pragma unroll
            for (int r = 0; r < 4; ++r)
                XC2[tau][(m * 16 + rbase + r) * 136 + ch] = (_Float16)silu_f(acc[r] + bv);
        } else {
            const int ch = (n - 8) * 16 + fcol;
#pragma unroll
            for (int r = 0; r < 4; ++r)
                ZS2[tau][(m * 16 + rbase + r) * 128 + ch] = (_Float16)silu_f(acc[r]);
        }
    }
    __syncthreads();

    // ---- phase C: 40 MFMA tile-tasks (both tiles) -> DE (softplus) | BC ----
#pragma unroll
    for (int i = 0; i < 5; ++i) {
        const int tt = wv + 8 * i;
        const int tau = (tt >= 20) ? 1 : 0, tid = tt - 20 * tau;
        const int m = tid & 1, n = tid >> 1;
        f32x4 acc = {0.f, 0.f, 0.f, 0.f};
#pragma unroll
        for (int ks = 0; ks < 4; ++ks) {
            const int ko = ks * 32 + kq * 8;
            f16x8 af = *(const f16x8*)&XC2[tau][(m * 16 + fcol) * 136 + ko];
            f16x8 bf = *(const f16x8*)&WT[(n * 16 + fcol) * 128 + ko];
            acc = __builtin_amdgcn_mfma_f32_16x16x32_f16(af, bf, acc, 0, 0, 0);
        }
        if (n < 8) {
            const int ch = n * 16 + fcol;
            const float db = dt_b[ch];
#pragma unroll
            for (int r = 0; r < 4; ++r)
                DE2[tau][(m * 16 + rbase + r) * 128 + ch] = (_Float16)sp2_f(acc[r] + db);
        } else {
            const int jb = (n - 8) * 16 + fcol;
#pragma unroll
            for (int r = 0; r < 4; ++r)
                BC2[tau][(m * 16 + rbase + r) * 32 + jb] = acc[r];
        }
    }
    __syncthreads();

    // ---- phase E: both segments scan concurrently (all 8 waves busy) ----
    f32x2 h2[4], P2[4], K2[4];
#pragma unroll
    for (int k = 0; k < 4; ++k) { h2[k] = splat2(0.f); P2[k] = splat2(1.f); K2[k] = splat2(0.f); }
    float gsum = 0.f;
    {
        const _Float16* DEw = DE2[wg];
        const _Float16* ZSw = ZS2[wg];
        const _Float16* XCw = XC2[wg];
        const float*    BCw = BC2[wg];
        auto scan_loop = [&](bool needpk) {
            for (int l = 0; l < TILE; ++l) {
                const float de = (float)DEw[l * 128 + dd];
                const float zs = (float)ZSw[l * 128 + dd];
                const float xc = (float)XCw[l * 136 + dd];
                const float du = de * xc;
                f32x2 E2[4];
                if (structured) {              // states 8g+1..8g+8: powers of r
                    const float r = exp2f(de * -1.44269504f);
                    const float t1 = exp2f(de * c1);   // r^(8g+1)
                    const float r2 = r * r;
                    E2[0] = (f32x2){t1, t1 * r};
                    const f32x2 r2s = splat2(r2);
                    E2[1] = E2[0] * r2s;
                    E2[2] = E2[1] * r2s;
                    E2[3] = E2[2] * r2s;
                } else {                       // cold generic path
#pragma unroll
                    for (int k = 0; k < 4; ++k) {
                        float e0 = exp2f(de * (-__expf(A_log[dd * 16 + g * 8 + 2 * k])) * 1.44269504f);
                        float e1 = exp2f(de * (-__expf(A_log[dd * 16 + g * 8 + 2 * k + 1])) * 1.44269504f);
                        E2[k] = (f32x2){e0, e1};
                    }
                }
                const float4 Bq0 = *(const float4*)&BCw[l * 32 + g * 8];
                const float4 Bq1 = *(const float4*)&BCw[l * 32 + g * 8 + 4];
                const float4 Cq0 = *(const float4*)&BCw[l * 32 + 16 + g * 8];
                const float4 Cq1 = *(const float4*)&BCw[l * 32 + 16 + g * 8 + 4];
                const f32x2 B2[4] = {{Bq0.x, Bq0.y}, {Bq0.z, Bq0.w}, {Bq1.x, Bq1.y}, {Bq1.z, Bq1.w}};
                const f32x2 C2[4] = {{Cq0.x, Cq0.y}, {Cq0.z, Cq0.w}, {Cq1.x, Cq1.y}, {Cq1.z, Cq1.w}};
                const f32x2 dus = splat2(du), zss = splat2(zs);
                f32x2 yp2 = splat2(0.f);
#pragma unroll
                for (int k = 0; k < 4; ++k) {
                    h2[k] = fma2(E2[k], h2[k], dus * B2[k]);
                    yp2 = fma2(h2[k], C2[k], yp2);
                    if (needpk) {
                        P2[k] = P2[k] * E2[k];
                        K2[k] = fma2(zss, C2[k] * P2[k], K2[k]);
                    }
                }
                float yp = yp2.x + yp2.y;
                const float y = yp + __shfl_xor(yp, 1);
                gsum += fmaf(xc, dskip, y) * zs;
            }
        };
        if (sidx == 0) scan_loop(false);
        else           scan_loop(true);
    }

    // ---- segment summary writeout (packed QPK) ----
    {
        const size_t sb = (size_t)sidx * Bn + b;
#pragma unroll
        for (int k = 0; k < 4; ++k) {
            const int p = g * 4 + k;
            f16x8 v;
            v[0] = (_Float16)h2[k].x; v[1] = (_Float16)h2[k].y;
            v[2] = (_Float16)P2[k].x; v[3] = (_Float16)P2[k].y;
            v[4] = (_Float16)K2[k].x; v[5] = (_Float16)K2[k].y;
            v[6] = (_Float16)0.f;     v[7] = (_Float16)0.f;
            QPK[(sb * 8 + p) * 128 + dd] = v;
        }
        if (g == 0) GS[sb * 128 + dd] = gsum;
        if (jp == 3 && wg == 1) {
            const float zs_last = (float)ZS2[1][(TILE - 1) * 128 + dd];
            const float xc_last = (float)XC2[1][(TILE - 1) * 136 + dd];
#pragma unroll
            for (int k = 0; k < 8; ++k)
                CZ[((size_t)b * 16 + g * 8 + k) * 128 + dd] =
                    zs_last * BC2[1][(TILE - 1) * 32 + 16 + g * 8 + k];
            if (g == 0) SL[(size_t)b * 128 + dd] = zs_last * xc_last * dskip;
        }
    }
}

// ---- stitch: chain packed segment summaries, out_proj, fused keys ----
template<int NS>
__global__ __launch_bounds__(128)
void stitch(const f16x8* __restrict__ QPK, const float* __restrict__ GS,
            const float* __restrict__ CZ, const float* __restrict__ SL,
            const float* __restrict__ out_proj_w,
            const float* __restrict__ k_w, const float* __restrict__ k_b,
            float* __restrict__ pooled, float* __restrict__ keysT, int Bn)
{
    const int b = blockIdx.x, d = threadIdx.x;
    __shared__ float gb[256];
    __shared__ float pl[128];

    float h[16];
    float gsum = GS[(size_t)b * 128 + d];          // s = 0: h0 = 0
#pragma unroll
    for (int p = 0; p < 8; ++p) {
        f16x8 v = QPK[((size_t)b * 8 + p) * 128 + d];
        h[2 * p] = (float)v[0]; h[2 * p + 1] = (float)v[1];
    }
#pragma unroll
    for (int s = 1; s < NS; ++s) {
        const size_t sb = (size_t)s * Bn + b;
        gsum += GS[sb * 128 + d];
        float corr = 0.f;
#pragma unroll
        for (int p = 0; p < 8; ++p) {
            f16x8 v = QPK[(sb * 8 + p) * 128 + d];
            corr = fmaf((float)v[4], h[2 * p], corr);
            corr = fmaf((float)v[5], h[2 * p + 1], corr);
            h[2 * p]     = fmaf((float)v[2], h[2 * p],     (float)v[0]);
            h[2 * p + 1] = fmaf((float)v[3], h[2 * p + 1], (float)v[1]);
        }
        gsum += corr;
    }
    float glast = SL[(size_t)b * 128 + d];
#pragma unroll
    for (int n = 0; n < 16; ++n)
        glast = fmaf(CZ[((size_t)b * 16 + n) * 128 + d], h[n], glast);

    gb[d] = gsum * (1.f / (float)L_SEQ);
    gb[128 + d] = glast;
    __syncthreads();
    {
        const int half = d >> 6, oc = d & 63;
        const float* gbp = &gb[half * 128];
        float s = 0.f;
#pragma unroll 16
        for (int i = 0; i < 128; ++i) s = fmaf(gbp[i], out_proj_w[i * 64 + oc], s);
        pooled[(size_t)b * 128 + d] = s;
        pl[d] = s;
    }
    __syncthreads();
    if (d < 64) {
        float s = k_b[d];
#pragma unroll 16
        for (int i = 0; i < 128; ++i) s = fmaf(pl[i], k_w[i * 64 + d], s);
        keysT[(size_t)d * Bn + b] = s;
    }
}

// ---- qk: 2 queries per block; out[n, m0..m0+3] via float4 keysT loads ----
__global__ __launch_bounds__(128)
void qk_kernel(const float* __restrict__ pooled, const int* __restrict__ idx,
               const float* __restrict__ q_w, const float* __restrict__ q_b,
               const float* __restrict__ keysT, float* __restrict__ out, int B, int N)
{
    const int n0 = blockIdx.x * 2, t = threadIdx.x;
    const int n1 = n0 + 1;
    const bool has1 = (n1 < N);
    __shared__ float p0[128], p1[128];
    __shared__ float q0[64], q1[64];
    const int bi0 = idx[n0];
    const int bi1 = has1 ? idx[n1] : bi0;
    p0[t] = pooled[(size_t)bi0 * 128 + t];
    p1[t] = pooled[(size_t)bi1 * 128 + t];
    __syncthreads();
    if (t < 64) {
        float s = q_b[t];
#pragma unroll
        for (int i = 0; i < 128; ++i) s = fmaf(p0[i], q_w[i * 64 + t], s);
        q0[t] = s;
    } else {
        const int tt = t - 64;
        float s = q_b[tt];
#pragma unroll
        for (int i = 0; i < 128; ++i) s = fmaf(p1[i], q_w[i * 64 + tt], s);
        q1[tt] = s;
    }
    __syncthreads();
    for (int m0 = t * 4; m0 < B; m0 += 512) {
        f32x4 a0 = {0.f, 0.f, 0.f, 0.f}, a1 = {0.f, 0.f, 0.f, 0.f};
#pragma unroll 8
        for (int i = 0; i < 64; ++i) {
            const float4 kv = *(const float4*)&keysT[(size_t)i * B + m0];
            const float qa = q0[i], qb = q1[i];
            a0[0] = fmaf(qa, kv.x, a0[0]); a0[1] = fmaf(qa, kv.y, a0[1]);
            a0[2] = fmaf(qa, kv.z, a0[2]); a0[3] = fmaf(qa, kv.w, a0[3]);
            a1[0] = fmaf(qb, kv.x, a1[0]); a1[1] = fmaf(qb, kv.y, a1[1]);
            a1[2] = fmaf(qb, kv.z, a1[2]); a1[3] = fmaf(qb, kv.w, a1[3]);
        }
        *(f32x4*)&out[(size_t)n0 * B + m0] = a0;
        if (has1) *(f32x4*)&out[(size_t)n1 * B + m0] = a1;
    }
}

// ============================ LAUNCH ============================

extern "C" void kernel_launch(void* const* d_in, const int* in_sizes, int n_in,
                              void* d_out, int out_size, void* d_ws, size_t ws_size,
                              hipStream_t stream)
{
    const float* reads      = (const float*)d_in[0];
    const int*   idx        = (const int*)d_in[1];
    const float* exp_w      = (const float*)d_in[2];
    const float* exp_b      = (const float*)d_in[3];
    const float* in_proj_w  = (const float*)d_in[4];
    const float* conv_w     = (const float*)d_in[5];
    const float* conv_b     = (const float*)d_in[6];
    const float* x_proj_w   = (const float*)d_in[7];
    const float* dt_w       = (const float*)d_in[8];
    const float* dt_b       = (const float*)d_in[9];
    const float* A_log      = (const float*)d_in[10];
    const float* D_skip     = (const float*)d_in[11];
    const float* out_proj_w = (const float*)d_in[12];
    const float* q_w        = (const float*)d_in[13];
    const float* q_b        = (const float*)d_in[14];
    const float* k_w        = (const float*)d_in[15];
    const float* k_b        = (const float*)d_in[16];

    const int B = in_sizes[0] / (L_SEQ * 4);
    const int N = in_sizes[1];

    char* wsb = (char*)d_ws;
    size_t off = 0;
    auto alloc = [&](size_t bytes) {
        size_t o = off;
        off = (off + bytes + 255) & ~(size_t)255;
        return o;
    };

    float*     pooled = (float*)(wsb + alloc((size_t)B * 128 * 4));
    float*     keysT  = (float*)(wsb + alloc((size_t)B * 64 * 4));
    _Float16*  WT     = (_Float16*)(wsb + alloc(160 * 128 * 2));
    _Float16*  W2     = (_Float16*)(wsb + alloc(256 * 32 * 2));
    float*     bias2  = (float*)(wsb + alloc(128 * 4));

    const size_t pairs = (size_t)B * NSEG * 8 * 128;
    f16x8* QPK = (f16x8*)(wsb + alloc(pairs * 16));
    float* GS  = (float*)(wsb + alloc((size_t)B * NSEG * 128 * 4));
    float* CZ  = (float*)(wsb + alloc((size_t)B * 16 * 128 * 4));
    float* SL  = (float*)(wsb + alloc((size_t)B * 128 * 4));

    k_prep<<<6, 256, 0, stream>>>(exp_w, exp_b, in_proj_w, x_proj_w, dt_w,
                                  conv_w, conv_b, WT, W2, bias2);
    mamba_seg2<<<B * 4, 512, 0, stream>>>(reads, WT, W2, bias2, dt_b,
                                          A_log, D_skip, QPK, GS, CZ, SL, B);
    stitch<NSEG><<<B, 128, 0, stream>>>(QPK, GS, CZ, SL, out_proj_w, k_w, k_b,
                                        pooled, keysT, B);
    qk_kernel<<<(N + 1) / 2, 128, 0, stream>>>(pooled, idx, q_w, q_b, keysT,
                                               (float*)d_out, B, N);
}

// Round 12
// 135.675 us; speedup vs baseline: 1.0872x; 1.0872x over previous
//
#include <hip/hip_runtime.h>
#include <math.h>

#define L_SEQ 256
#define TILE 16
#define NSEG 16

typedef __attribute__((ext_vector_type(2))) float f32x2;
typedef __attribute__((ext_vector_type(4))) float f32x4;
typedef __attribute__((ext_vector_type(8))) _Float16 f16x8;
typedef __attribute__((ext_vector_type(2))) _Float16 f16x2;

__device__ __forceinline__ f32x2 fma2(f32x2 a, f32x2 b, f32x2 c) {
    return __builtin_elementwise_fma(a, b, c);
}
__device__ __forceinline__ f32x2 splat2(float x) { f32x2 v = {x, x}; return v; }
__device__ __forceinline__ float silu_f(float x) { return x / (1.f + __expf(-x)); }
__device__ __forceinline__ float sp2_f(float x) {
    return log2f(1.f + exp2f(x * 1.44269504f)) * 0.69314718f;
}

// ---- prep (one launch, 6 blocks):
//  blocks 0..4: WT[160][128] f16 = [x_proj[:,:4]@dt_w | x_proj[:,4:36]]^T
//  block 5:     W2[256][32] f16 (conv+expansion+in_proj folded) + bias2
__global__ __launch_bounds__(256)
void k_prep(const float* __restrict__ exp_w, const float* __restrict__ exp_b,
            const float* __restrict__ in_proj_w, const float* __restrict__ x_proj_w,
            const float* __restrict__ dt_w,
            const float* __restrict__ conv_w, const float* __restrict__ conv_b,
            _Float16* __restrict__ WT, _Float16* __restrict__ W2, float* __restrict__ bias2)
{
    const int t = threadIdx.x, blk = blockIdx.x;
    if (blk < 5) {
        const int base = blk * 4096;
        for (int i = base + t; i < base + 4096; i += 256) {
            const int row = i >> 7, k = i & 127;
            float v;
            if (row < 128) {
                v = x_proj_w[k * 36 + 0] * dt_w[row]
                  + x_proj_w[k * 36 + 1] * dt_w[128 + row]
                  + x_proj_w[k * 36 + 2] * dt_w[256 + row]
                  + x_proj_w[k * 36 + 3] * dt_w[384 + row];
            } else {
                v = x_proj_w[k * 36 + 4 + (row - 128)];
            }
            WT[i] = (_Float16)v;
        }
    } else {
        // thread t<128 -> xc channel d=t ; t>=128 -> z channel d=t-128
        const int d = t & 127;
        const int col = (t < 128) ? d : (128 + d);
        float w0 = 0, w1 = 0, w2 = 0, w3 = 0, bb = 0;
        for (int k = 0; k < 64; ++k) {
            float w = in_proj_w[k * 256 + col];
            w0 = fmaf(exp_w[k], w, w0);
            w1 = fmaf(exp_w[64 + k], w, w1);
            w2 = fmaf(exp_w[128 + k], w, w2);
            w3 = fmaf(exp_w[192 + k], w, w3);
            bb = fmaf(exp_b[k], w, bb);
        }
        const float wx[4] = {w0, w1, w2, w3};
        if (t < 128) {
            for (int j = 0; j < 32; ++j) {
                float v = 0.f;
                if (j < 16)      v = conv_w[d * 4 + (j >> 2)] * wx[j & 3];
                else if (j < 20) v = conv_w[d * 4 + (j - 16)] * bb;
                W2[d * 32 + j] = (_Float16)v;
            }
            bias2[d] = conv_b[d];
        } else {
            for (int j = 0; j < 32; ++j) {
                float v = 0.f;
                if (j >= 12 && j < 16) v = wx[j - 12];
                else if (j == 19)      v = bb;
                W2[(128 + d) * 32 + j] = (_Float16)v;
            }
        }
    }
}

// ---- fused Mamba: grid = B*16 blocks x 256 threads, one 16-step segment each ----
// Phase E uses ALL 4 waves (256 thr = 128 channels x 2 lanes); LDS ~15.7 KB.
__global__ __launch_bounds__(256, 6)
void mamba_seg(const float* __restrict__ reads,
               const _Float16* __restrict__ WT, const _Float16* __restrict__ W2,
               const float* __restrict__ bias2, const float* __restrict__ dt_b,
               const float* __restrict__ A_log, const float* __restrict__ D_skip,
               f16x2* __restrict__ Qg, f16x2* __restrict__ Pg, f16x2* __restrict__ Kg,
               float* __restrict__ GS, float* __restrict__ CZ, float* __restrict__ SL,
               int Bn)
{
    const int bx = blockIdx.x;
    const int b = bx >> 4, sidx = bx & 15;
    const int l_off = sidx * TILE;
    const int t = threadIdx.x;
    const int dd = t >> 1, g = t & 1;          // phase E: channel, state-half

    __shared__ __align__(16) _Float16 F[TILE * 40];    // features, K-padded
    __shared__ __align__(16) _Float16 XC[TILE * 136];  // conv out (silu), fp16
    __shared__ __align__(16) float    BC[TILE * 32];   // B(16)|C(16) per step
    __shared__ _Float16               ZS[TILE * 128];  // silu(z)
    __shared__ _Float16               DE[TILE * 128];  // delta

    // phase-E per-lane params
    const float dskip = D_skip[dd];
    const float c1 = -1.44269504f * (float)(8 * g + 1);   // r^(8g+1)
    bool structured = true;
#pragma unroll
    for (int k = 0; k < 8; ++k) {
        float a = -__expf(A_log[dd * 16 + g * 8 + k]);
        structured = structured && (fabsf(a + (float)(g * 8 + k + 1)) < 1e-3f);
    }

    // ---- build F[16][40]: taps(16) | bias indicators(4) | pad ----
    for (int i = t; i < TILE * 40; i += 256) {
        const int l = i / 40, j = i - l * 40;
        _Float16 v = (_Float16)0.f;
        if (j < 16) {
            const int row = l_off + l - 3 + (j >> 2);
            if (row >= 0) v = (_Float16)reads[((size_t)b * L_SEQ + row) * 4 + (j & 3)];
        } else if (j < 20) {
            v = (l_off + l - 3 + (j - 16) >= 0) ? (_Float16)1.f : (_Float16)0.f;
        }
        F[i] = v;
    }
    __syncthreads();

    const int lane = t & 63, wv = t >> 6;
    const int fcol = lane & 15, kq = lane >> 4, rbase = kq * 4;

    // ---- phase A: MFMA [16 x 256] = F[16x32] @ W2^T ; silu -> XC, ZS ----
#pragma unroll
    for (int i = 0; i < 4; ++i) {
        const int n = wv + 4 * i;              // 16 tasks over 4 waves
        f16x8 af = *(const f16x8*)&F[fcol * 40 + kq * 8];
        f16x8 bf = *(const f16x8*)&W2[(n * 16 + fcol) * 32 + kq * 8];
        f32x4 acc = {0.f, 0.f, 0.f, 0.f};
        acc = __builtin_amdgcn_mfma_f32_16x16x32_f16(af, bf, acc, 0, 0, 0);
        if (n < 8) {
            const int ch = n * 16 + fcol;
            const float bv = bias2[ch];
#pragma unroll
            for (int r = 0; r < 4; ++r)
                XC[(rbase + r) * 136 + ch] = (_Float16)silu_f(acc[r] + bv);
        } else {
            const int ch = (n - 8) * 16 + fcol;
#pragma unroll
            for (int r = 0; r < 4; ++r)
                ZS[(rbase + r) * 128 + ch] = (_Float16)silu_f(acc[r]);
        }
    }
    __syncthreads();

    // ---- phase C: MFMA [16 x 160] = XC[16x128] @ WT^T -> DE (softplus) | BC ----
#pragma unroll
    for (int i = 0; i < 3; ++i) {
        const int n = wv + 4 * i;              // 10 tasks over 4 waves
        if (n < 10) {
            f32x4 acc = {0.f, 0.f, 0.f, 0.f};
#pragma unroll
            for (int ks = 0; ks < 4; ++ks) {
                const int ko = ks * 32 + kq * 8;
                f16x8 af = *(const f16x8*)&XC[fcol * 136 + ko];
                f16x8 bf = *(const f16x8*)&WT[(n * 16 + fcol) * 128 + ko];
                acc = __builtin_amdgcn_mfma_f32_16x16x32_f16(af, bf, acc, 0, 0, 0);
            }
            if (n < 8) {
                const int ch = n * 16 + fcol;
                const float db = dt_b[ch];
#pragma unroll
                for (int r = 0; r < 4; ++r)
                    DE[(rbase + r) * 128 + ch] = (_Float16)sp2_f(acc[r] + db);
            } else {
                const int jb = (n - 8) * 16 + fcol;
#pragma unroll
                for (int r = 0; r < 4; ++r)
                    BC[(rbase + r) * 32 + jb] = acc[r];
            }
        }
    }
    __syncthreads();

    // ---- phase E: 16-step serial scan; 2 lanes/channel, ALL waves active ----
    f32x2 h2[4], P2[4], K2[4];
#pragma unroll
    for (int k = 0; k < 4; ++k) { h2[k] = splat2(0.f); P2[k] = splat2(1.f); K2[k] = splat2(0.f); }
    float gsum = 0.f;
    {
        auto scan_loop = [&](bool needpk) {
            for (int l = 0; l < TILE; ++l) {
                const float de = (float)DE[l * 128 + dd];
                const float zs = (float)ZS[l * 128 + dd];
                const float xc = (float)XC[l * 136 + dd];
                const float du = de * xc;
                f32x2 E2[4];
                if (structured) {              // states 8g+1..8g+8: powers of r
                    const float r = exp2f(de * -1.44269504f);
                    const float t1 = exp2f(de * c1);   // r^(8g+1)
                    const float r2 = r * r;
                    E2[0] = (f32x2){t1, t1 * r};
                    const f32x2 r2s = splat2(r2);
                    E2[1] = E2[0] * r2s;
                    E2[2] = E2[1] * r2s;
                    E2[3] = E2[2] * r2s;
                } else {                       // cold generic path
#pragma unroll
                    for (int k = 0; k < 4; ++k) {
                        float e0 = exp2f(de * (-__expf(A_log[dd * 16 + g * 8 + 2 * k])) * 1.44269504f);
                        float e1 = exp2f(de * (-__expf(A_log[dd * 16 + g * 8 + 2 * k + 1])) * 1.44269504f);
                        E2[k] = (f32x2){e0, e1};
                    }
                }
                const float4 Bq0 = *(const float4*)&BC[l * 32 + g * 8];
                const float4 Bq1 = *(const float4*)&BC[l * 32 + g * 8 + 4];
                const float4 Cq0 = *(const float4*)&BC[l * 32 + 16 + g * 8];
                const float4 Cq1 = *(const float4*)&BC[l * 32 + 16 + g * 8 + 4];
                const f32x2 B2[4] = {{Bq0.x, Bq0.y}, {Bq0.z, Bq0.w}, {Bq1.x, Bq1.y}, {Bq1.z, Bq1.w}};
                const f32x2 C2[4] = {{Cq0.x, Cq0.y}, {Cq0.z, Cq0.w}, {Cq1.x, Cq1.y}, {Cq1.z, Cq1.w}};
                const f32x2 dus = splat2(du), zss = splat2(zs);
                f32x2 yp2 = splat2(0.f);
#pragma unroll
                for (int k = 0; k < 4; ++k) {
                    h2[k] = fma2(E2[k], h2[k], dus * B2[k]);
                    yp2 = fma2(h2[k], C2[k], yp2);
                    if (needpk) {
                        P2[k] = P2[k] * E2[k];
                        K2[k] = fma2(zss, C2[k] * P2[k], K2[k]);
                    }
                }
                float yp = yp2.x + yp2.y;
                const float y = yp + __shfl_xor(yp, 1);
                gsum += fmaf(xc, dskip, y) * zs;
            }
        };
        if (sidx == 0) scan_loop(false);
        else           scan_loop(true);
    }

    // ---- segment summary writeout (LDS still holds the tile) ----
    {
        const size_t sb = (size_t)sidx * Bn + b;
#pragma unroll
        for (int k = 0; k < 4; ++k) {
            const size_t o = (sb * 8 + g * 4 + k) * 128 + dd;   // pair p = g*4+k
            Qg[o] = (f16x2){(_Float16)h2[k].x, (_Float16)h2[k].y};
            if (sidx != 0) {
                Pg[o] = (f16x2){(_Float16)P2[k].x, (_Float16)P2[k].y};
                Kg[o] = (f16x2){(_Float16)K2[k].x, (_Float16)K2[k].y};
            }
        }
        if (g == 0) GS[sb * 128 + dd] = gsum;
        if (sidx == NSEG - 1) {
            const float zs_last = (float)ZS[(TILE - 1) * 128 + dd];
            const float xc_last = (float)XC[(TILE - 1) * 136 + dd];
#pragma unroll
            for (int k = 0; k < 8; ++k)
                CZ[((size_t)b * 16 + g * 8 + k) * 128 + dd] =
                    zs_last * BC[(TILE - 1) * 32 + 16 + g * 8 + k];
            if (g == 0) SL[(size_t)b * 128 + dd] = zs_last * xc_last * dskip;
        }
    }
}

// ---- stitch: chain segment summaries, out_proj, fused keys ----
template<int NS>
__global__ __launch_bounds__(128)
void stitch(const f16x2* __restrict__ Qg, const f16x2* __restrict__ Pg,
            const f16x2* __restrict__ Kg, const float* __restrict__ GS,
            const float* __restrict__ CZ, const float* __restrict__ SL,
            const float* __restrict__ out_proj_w,
            const float* __restrict__ k_w, const float* __restrict__ k_b,
            float* __restrict__ pooled, float* __restrict__ keysT, int Bn)
{
    const int b = blockIdx.x, d = threadIdx.x;
    __shared__ float gb[256];
    __shared__ float pl[128];

    float h[16];
    float gsum = GS[(size_t)b * 128 + d];          // s = 0: h0 = 0
#pragma unroll
    for (int p = 0; p < 8; ++p) {
        f16x2 q = Qg[((size_t)b * 8 + p) * 128 + d];
        h[2 * p] = (float)q[0]; h[2 * p + 1] = (float)q[1];
    }
#pragma unroll
    for (int s = 1; s < NS; ++s) {
        const size_t sb = (size_t)s * Bn + b;
        gsum += GS[sb * 128 + d];
        float corr = 0.f;
#pragma unroll
        for (int p = 0; p < 8; ++p) {
            const size_t o = (sb * 8 + p) * 128 + d;
            f16x2 qv = Qg[o], pv = Pg[o], kv = Kg[o];
            corr = fmaf((float)kv[0], h[2 * p], corr);
            corr = fmaf((float)kv[1], h[2 * p + 1], corr);
            h[2 * p]     = fmaf((float)pv[0], h[2 * p],     (float)qv[0]);
            h[2 * p + 1] = fmaf((float)pv[1], h[2 * p + 1], (float)qv[1]);
        }
        gsum += corr;
    }
    float glast = SL[(size_t)b * 128 + d];
#pragma unroll
    for (int n = 0; n < 16; ++n)
        glast = fmaf(CZ[((size_t)b * 16 + n) * 128 + d], h[n], glast);

    gb[d] = gsum * (1.f / (float)L_SEQ);
    gb[128 + d] = glast;
    __syncthreads();
    {
        const int half = d >> 6, oc = d & 63;
        const float* gbp = &gb[half * 128];
        float s = 0.f;
#pragma unroll 16
        for (int i = 0; i < 128; ++i) s = fmaf(gbp[i], out_proj_w[i * 64 + oc], s);
        pooled[(size_t)b * 128 + d] = s;
        pl[d] = s;
    }
    __syncthreads();
    if (d < 64) {
        float s = k_b[d];
#pragma unroll 16
        for (int i = 0; i < 128; ++i) s = fmaf(pl[i], k_w[i * 64 + d], s);
        keysT[(size_t)d * Bn + b] = s;
    }
}

// ---- qk: 2 queries per block; float4 keysT loads ----
__global__ __launch_bounds__(128)
void qk_kernel(const float* __restrict__ pooled, const int* __restrict__ idx,
               const float* __restrict__ q_w, const float* __restrict__ q_b,
               const float* __restrict__ keysT, float* __restrict__ out, int B, int N)
{
    const int n0 = blockIdx.x * 2, t = threadIdx.x;
    const int n1 = n0 + 1;
    const bool has1 = (n1 < N);
    __shared__ float p0[128], p1[128];
    __shared__ float q0[64], q1[64];
    const int bi0 = idx[n0];
    const int bi1 = has1 ? idx[n1] : bi0;
    p0[t] = pooled[(size_t)bi0 * 128 + t];
    p1[t] = pooled[(size_t)bi1 * 128 + t];
    __syncthreads();
    if (t < 64) {
        float s = q_b[t];
#pragma unroll
        for (int i = 0; i < 128; ++i) s = fmaf(p0[i], q_w[i * 64 + t], s);
        q0[t] = s;
    } else {
        const int tt = t - 64;
        float s = q_b[tt];
#pragma unroll
        for (int i = 0; i < 128; ++i) s = fmaf(p1[i], q_w[i * 64 + tt], s);
        q1[tt] = s;
    }
    __syncthreads();
    for (int m0 = t * 4; m0 < B; m0 += 512) {
        f32x4 a0 = {0.f, 0.f, 0.f, 0.f}, a1 = {0.f, 0.f, 0.f, 0.f};
#pragma unroll 8
        for (int i = 0; i < 64; ++i) {
            const float4 kv = *(const float4*)&keysT[(size_t)i * B + m0];
            const float qa = q0[i], qb = q1[i];
            a0[0] = fmaf(qa, kv.x, a0[0]); a0[1] = fmaf(qa, kv.y, a0[1]);
            a0[2] = fmaf(qa, kv.z, a0[2]); a0[3] = fmaf(qa, kv.w, a0[3]);
            a1[0] = fmaf(qb, kv.x, a1[0]); a1[1] = fmaf(qb, kv.y, a1[1]);
            a1[2] = fmaf(qb, kv.z, a1[2]); a1[3] = fmaf(qb, kv.w, a1[3]);
        }
        *(f32x4*)&out[(size_t)n0 * B + m0] = a0;
        if (has1) *(f32x4*)&out[(size_t)n1 * B + m0] = a1;
    }
}

// ============================ LAUNCH ============================

extern "C" void kernel_launch(void* const* d_in, const int* in_sizes, int n_in,
                              void* d_out, int out_size, void* d_ws, size_t ws_size,
                              hipStream_t stream)
{
    const float* reads      = (const float*)d_in[0];
    const int*   idx        = (const int*)d_in[1];
    const float* exp_w      = (const float*)d_in[2];
    const float* exp_b      = (const float*)d_in[3];
    const float* in_proj_w  = (const float*)d_in[4];
    const float* conv_w     = (const float*)d_in[5];
    const float* conv_b     = (const float*)d_in[6];
    const float* x_proj_w   = (const float*)d_in[7];
    const float* dt_w       = (const float*)d_in[8];
    const float* dt_b       = (const float*)d_in[9];
    const float* A_log      = (const float*)d_in[10];
    const float* D_skip     = (const float*)d_in[11];
    const float* out_proj_w = (const float*)d_in[12];
    const float* q_w        = (const float*)d_in[13];
    const float* q_b        = (const float*)d_in[14];
    const float* k_w        = (const float*)d_in[15];
    const float* k_b        = (const float*)d_in[16];

    const int B = in_sizes[0] / (L_SEQ * 4);
    const int N = in_sizes[1];

    char* wsb = (char*)d_ws;
    size_t off = 0;
    auto alloc = [&](size_t bytes) {
        size_t o = off;
        off = (off + bytes + 255) & ~(size_t)255;
        return o;
    };

    float*     pooled = (float*)(wsb + alloc((size_t)B * 128 * 4));
    float*     keysT  = (float*)(wsb + alloc((size_t)B * 64 * 4));
    _Float16*  WT     = (_Float16*)(wsb + alloc(160 * 128 * 2));
    _Float16*  W2     = (_Float16*)(wsb + alloc(256 * 32 * 2));
    float*     bias2  = (float*)(wsb + alloc(128 * 4));

    const size_t pairs = (size_t)B * NSEG * 8 * 128;
    f16x2* Qg = (f16x2*)(wsb + alloc(pairs * 4));
    f16x2* Pg = (f16x2*)(wsb + alloc(pairs * 4));
    f16x2* Kg = (f16x2*)(wsb + alloc(pairs * 4));
    float* GS = (float*)(wsb + alloc((size_t)B * NSEG * 128 * 4));
    float* CZ = (float*)(wsb + alloc((size_t)B * 16 * 128 * 4));
    float* SL = (float*)(wsb + alloc((size_t)B * 128 * 4));

    k_prep<<<6, 256, 0, stream>>>(exp_w, exp_b, in_proj_w, x_proj_w, dt_w,
                                  conv_w, conv_b, WT, W2, bias2);
    mamba_seg<<<B * NSEG, 256, 0, stream>>>(reads, WT, W2, bias2, dt_b,
                                            A_log, D_skip, Qg, Pg, Kg,
                                            GS, CZ, SL, B);
    stitch<NSEG><<<B, 128, 0, stream>>>(Qg, Pg, Kg, GS, CZ, SL, out_proj_w, k_w, k_b,
                                        pooled, keysT, B);
    qk_kernel<<<(N + 1) / 2, 128, 0, stream>>>(pooled, idx, q_w, q_b, keysT,
                                               (float*)d_out, B, N);
}